// Round 1
// baseline (3008.178 us; speedup 1.0000x reference)
//
#include <hip/hip_runtime.h>
#include <cstdint>
#include <cstddef>

#define T_STEPS 16
#define BB 512
#define NF 1024
#define NI 256
#define NH 2048
#define KSTEPS 5

typedef __bf16 bf16;
typedef __bf16 bf16x8 __attribute__((ext_vector_type(8)));
typedef __bf16 bf16x4 __attribute__((ext_vector_type(4)));
typedef float f32x4 __attribute__((ext_vector_type(4)));

enum { EPI_BF16 = 0, EPI_F32 = 1, EPI_TEMPS = 2, EPI_W1 = 3, EPI_SHRINK = 4 };

__device__ __forceinline__ void gload_lds16(const bf16* g, bf16* l) {
  __builtin_amdgcn_global_load_lds(
      (const __attribute__((address_space(1))) void*)g,
      (__attribute__((address_space(3))) void*)l, 16, 0, 0);
}

// faithful multi-branch prox of w0*|x| + w1*|x - a1|
__device__ __forceinline__ float soft_l1_l1(float z, float w0, float w1, float a1) {
  bool c = (0.0f <= a1);
  float a0s = c ? 0.0f : a1;
  float a1s = c ? a1 : 0.0f;
  float w0s = c ? w0 : w1;
  float w1s = c ? w1 : w0;
  if (z >= a1s + w0s + w1s) return z - w0s - w1s;
  if (z >= a1s + w0s - w1s) return a1s;
  if (z >= a0s + w0s - w1s) return z - w0s + w1s;
  if (z >= a0s - w0s - w1s) return a0s;
  return z + w0s + w1s;
}

// C[m,n] = sum_k Aop[m,k]*Bop[n,k]; Aop:[M,Kd] row-major, Bop:[N,Kd] row-major (both K-contiguous).
// 256 threads = 4 waves (2x2), each wave computes (BM/2)x(BN/2) via 16x16x32 bf16 MFMA.
template<int BM, int BN, int EPI>
__global__ void gemm_bt(const bf16* __restrict__ Ag, const bf16* __restrict__ Bg,
                        int N, int Kd,
                        bf16* __restrict__ outb, float* __restrict__ outf,
                        bf16* __restrict__ out2,
                        const float* __restrict__ srcf,
                        const bf16* __restrict__ xv, const bf16* __restrict__ a1p,
                        const float* __restrict__ alpha,
                        const float* __restrict__ lam0, const float* __restrict__ lam1,
                        int inv_alpha)
{
  constexpr int WM = BM/2, WN = BN/2, FM = WM/16, FN = WN/16;
  __shared__ bf16 As[BM*32];
  __shared__ bf16 Bs[BN*32];
  const int tid = threadIdx.x;
  const int lane = tid & 63;
  const int wid = tid >> 6;
  const int wr = wid >> 1, wc = wid & 1;
  const int bm0 = blockIdx.x * BM;
  const int bn0 = blockIdx.y * BN;
  const int r16 = lane & 15, q16 = lane >> 4;

  f32x4 zero = {0.f, 0.f, 0.f, 0.f};
  f32x4 acc[FM][FN];
#pragma unroll
  for (int i = 0; i < FM; i++)
#pragma unroll
    for (int j = 0; j < FN; j++) acc[i][j] = zero;

  for (int kt = 0; kt < Kd; kt += 32) {
    __syncthreads();
#pragma unroll
    for (int it = 0; it < BM/64; ++it) {
      int idx = it*256 + tid;
      gload_lds16(Ag + (size_t)(bm0 + (idx >> 2))*Kd + kt + (idx & 3)*8, &As[idx*8]);
    }
#pragma unroll
    for (int it = 0; it < BN/64; ++it) {
      int idx = it*256 + tid;
      gload_lds16(Bg + (size_t)(bn0 + (idx >> 2))*Kd + kt + (idx & 3)*8, &Bs[idx*8]);
    }
    __syncthreads();
    bf16x8 afr[FM], bfr[FN];
#pragma unroll
    for (int i = 0; i < FM; i++)
      afr[i] = *(const bf16x8*)&As[(wr*WM + i*16 + r16)*32 + q16*8];
#pragma unroll
    for (int j = 0; j < FN; j++)
      bfr[j] = *(const bf16x8*)&Bs[(wc*WN + j*16 + r16)*32 + q16*8];
#pragma unroll
    for (int i = 0; i < FM; i++)
#pragma unroll
      for (int j = 0; j < FN; j++)
        acc[i][j] = __builtin_amdgcn_mfma_f32_16x16x32_bf16(afr[i], bfr[j], acc[i][j], 0, 0, 0);
  }

  float scale = 1.f;
  if (inv_alpha) scale = 1.f / alpha[0];
  float w0 = 0.f, w1 = 0.f;
  if (EPI == EPI_SHRINK) { float al = alpha[0]; w0 = lam0[0]/al; w1 = lam1[0]/al; }

#pragma unroll
  for (int i = 0; i < FM; i++) {
#pragma unroll
    for (int j = 0; j < FN; j++) {
#pragma unroll
      for (int e = 0; e < 4; e++) {
        int m = bm0 + wr*WM + i*16 + q16*4 + e;
        int n = bn0 + wc*WN + j*16 + r16;
        size_t o = (size_t)m*N + n;
        float v = acc[i][j][e] * scale;
        if (EPI == EPI_BF16) {
          outb[o] = (bf16)v;
        } else if (EPI == EPI_F32) {
          outf[o] = v;
        } else if (EPI == EPI_TEMPS) {
          outb[o] = (bf16)v;
          out2[o] = (bf16)((m == n ? 1.f : 0.f) - v);
        } else if (EPI == EPI_W1) {
          outb[o] = (bf16)(srcf[o] - v);
        } else { // EPI_SHRINK
          float z = v + (float)xv[o];
          outb[o] = (bf16)soft_l1_l1(z, w0, w1, (float)a1p[o]);
        }
      }
    }
  }
}

__global__ void cast_f32_bf16(const float* __restrict__ in, bf16* __restrict__ out, int n) {
  int i = (blockIdx.x*blockDim.x + threadIdx.x) * 4;
  if (i + 4 <= n) {
    float4 v = *(const float4*)&in[i];
    bf16x4 p;
    p[0] = (bf16)v.x; p[1] = (bf16)v.y; p[2] = (bf16)v.z; p[3] = (bf16)v.w;
    *(bf16x4*)&out[i] = p;
  } else {
    for (; i < n; ++i) out[i] = (bf16)in[i];
  }
}

// out[c,r] = (bf16) in[r,c];  in: [R,C] f32 row-major -> out: [C,R] bf16 row-major
__global__ void transpose_cast(const float* __restrict__ in, bf16* __restrict__ out, int R, int C) {
  __shared__ float tile[32][33];
  int bx = blockIdx.x*32, by = blockIdx.y*32;
  int tx = threadIdx.x, ty = threadIdx.y;
  for (int i = ty; i < 32; i += 8) {
    int r = by + i, c = bx + tx;
    if (r < R && c < C) tile[i][tx] = in[(size_t)r*C + c];
  }
  __syncthreads();
  for (int i = ty; i < 32; i += 8) {
    int r = bx + i, c = by + tx;
    if (r < C && c < R) out[(size_t)r*R + c] = (bf16)tile[tx][i];
  }
}

extern "C" void kernel_launch(void* const* d_in, const int* in_sizes, int n_in,
                              void* d_out, int out_size, void* d_ws, size_t ws_size,
                              hipStream_t stream) {
  // inputs: 0 pre_input (unused: inp[1:] drops it), 1 raw, 2 A, 3 D, 4 G, 5 h_0,
  //         6 alpha, 7 lambda0, 8 lambda1, 9 K (fixed = 5)
  const float* rawf = (const float*)d_in[1];
  const float* Af   = (const float*)d_in[2];
  const float* Df   = (const float*)d_in[3];
  const float* Gf   = (const float*)d_in[4];
  const float* h0f  = (const float*)d_in[5];
  const float* alp  = (const float*)d_in[6];
  const float* l0   = (const float*)d_in[7];
  const float* l1   = (const float*)d_in[8];
  float* outp = (float*)d_out;

  char* w = (char*)d_ws;
  auto alloc = [&](size_t nelem) { bf16* p = (bf16*)w; w += (nelem*2 + 255) & ~(size_t)255; return p; };
  bf16* Abf  = alloc((size_t)NI*NF);
  bf16* At   = alloc((size_t)NF*NI);
  bf16* Dbf  = alloc((size_t)NF*NH);
  bf16* Dt   = alloc((size_t)NH*NF);
  bf16* Gt   = alloc((size_t)NH*NH);
  bf16* rawb = alloc((size_t)T_STEPS*BB*NF);
  bf16* AtA  = alloc((size_t)NF*NF);
  bf16* Vm   = alloc((size_t)NH*NI);
  bf16* M3t  = alloc((size_t)NH*NF);
  bf16* tmpb = alloc((size_t)NH*NH);
  bf16* Sm   = alloc((size_t)NH*NH);
  bf16* W1m  = alloc((size_t)NH*NH);
  bf16* X    = alloc((size_t)T_STEPS*BB*NI);
  bf16* A1   = alloc((size_t)BB*NH);
  bf16* H0   = alloc((size_t)BB*NH);
  bf16* Hb0  = alloc((size_t)BB*NH);
  bf16* Hb1  = alloc((size_t)BB*NH);
  bf16* HS   = alloc((size_t)T_STEPS*BB*NH);
  // XV (T*B x NH bf16 = 32 MB) lives in d_out: fully written before use, dead before
  // the final projection overwrites d_out.
  bf16* XV   = (bf16*)d_out;

  auto cgrid = [](int n){ return dim3((unsigned)((n/4 + 255)/256)); };
  cast_f32_bf16<<<cgrid(NI*NF), 256, 0, stream>>>(Af, Abf, NI*NF);
  cast_f32_bf16<<<cgrid(NF*NH), 256, 0, stream>>>(Df, Dbf, NF*NH);
  cast_f32_bf16<<<cgrid(T_STEPS*BB*NF), 256, 0, stream>>>(rawf, rawb, T_STEPS*BB*NF);
  cast_f32_bf16<<<cgrid(BB*NH), 256, 0, stream>>>(h0f, H0, BB*NH);
  transpose_cast<<<dim3(NF/32, NI/32), dim3(32,8), 0, stream>>>(Af, At, NI, NF);
  transpose_cast<<<dim3(NH/32, NF/32), dim3(32,8), 0, stream>>>(Df, Dt, NF, NH);
  transpose_cast<<<dim3(NH/32, NH/32), dim3(32,8), 0, stream>>>(Gf, Gt, NH, NH);

  // AtA[f1,f2] = sum_i A[i,f1]A[i,f2]
  gemm_bt<64,64,EPI_BF16><<<dim3(NF/64, NF/64), 256, 0, stream>>>(
      At, At, NF, NI, AtA, nullptr, nullptr, nullptr, nullptr, nullptr, alp, l0, l1, 0);
  // V[h,i] = (1/al) sum_f D[f,h]A[i,f]
  gemm_bt<64,64,EPI_BF16><<<dim3(NH/64, NI/64), 256, 0, stream>>>(
      Dt, Abf, NI, NF, Vm, nullptr, nullptr, nullptr, nullptr, nullptr, alp, l0, l1, 1);
  // M3t[h,f] = sum_f2 Dt[h,f2]AtA[f,f2] = (AtA@D)[f,h]  (AtA symmetric)
  gemm_bt<128,128,EPI_BF16><<<dim3(NH/128, NF/128), 256, 0, stream>>>(
      Dt, AtA, NF, NF, M3t, nullptr, nullptr, nullptr, nullptr, nullptr, alp, l0, l1, 0);
  // temp = (1/al) D^T (AtA D); S = I - temp (dual store)
  gemm_bt<128,128,EPI_TEMPS><<<dim3(NH/128, NH/128), 256, 0, stream>>>(
      Dt, M3t, NH, NF, tmpb, nullptr, Sm, nullptr, nullptr, nullptr, alp, l0, l1, 1);
  // W1 = G - temp@G
  gemm_bt<128,128,EPI_W1><<<dim3(NH/128, NH/128), 256, 0, stream>>>(
      tmpb, Gt, NH, NH, W1m, nullptr, nullptr, Gf, nullptr, nullptr, alp, l0, l1, 0);
  // X = raw @ A^T
  gemm_bt<64,64,EPI_BF16><<<dim3(T_STEPS*BB/64, NI/64), 256, 0, stream>>>(
      rawb, Abf, NI, NF, X, nullptr, nullptr, nullptr, nullptr, nullptr, alp, l0, l1, 0);
  // XV = X @ V^T
  gemm_bt<128,128,EPI_BF16><<<dim3(T_STEPS*BB/128, NH/128), 256, 0, stream>>>(
      X, Vm, NH, NI, XV, nullptr, nullptr, nullptr, nullptr, nullptr, alp, l0, l1, 0);

  const size_t HBsz = (size_t)BB*NH;
  const bf16* hp = H0;
  for (int t = 0; t < T_STEPS; ++t) {
    const bf16* xvt = XV + (size_t)t*HBsz;
    // a1 = h_prev @ G
    gemm_bt<64,64,EPI_BF16><<<dim3(BB/64, NH/64), 256, 0, stream>>>(
        hp, Gt, NH, NH, A1, nullptr, nullptr, nullptr, nullptr, nullptr, alp, l0, l1, 0);
    bf16* dsts[KSTEPS];
    for (int k = 0; k < KSTEPS; ++k) dsts[k] = (k & 1) ? Hb1 : Hb0;
    dsts[KSTEPS-1] = HS + (size_t)t*HBsz;
    // h = shrink(h_prev @ W1^T + xv)
    gemm_bt<64,64,EPI_SHRINK><<<dim3(BB/64, NH/64), 256, 0, stream>>>(
        hp, W1m, NH, NH, dsts[0], nullptr, nullptr, nullptr, xvt, A1, alp, l0, l1, 0);
    const bf16* cur = dsts[0];
    for (int k = 1; k < KSTEPS; ++k) {
      // h = shrink(xv + h @ S^T)
      gemm_bt<64,64,EPI_SHRINK><<<dim3(BB/64, NH/64), 256, 0, stream>>>(
          cur, Sm, NH, NH, dsts[k], nullptr, nullptr, nullptr, xvt, A1, alp, l0, l1, 0);
      cur = dsts[k];
    }
    hp = HS + (size_t)t*HBsz;
  }
  // z_hat = HS @ D^T (fp32 direct to d_out)
  gemm_bt<128,128,EPI_F32><<<dim3(T_STEPS*BB/128, NF/128), 256, 0, stream>>>(
      HS, Dbf, NF, NH, nullptr, outp, nullptr, nullptr, nullptr, nullptr, alp, l0, l1, 0);
}

// Round 2
// 1927.222 us; speedup vs baseline: 1.5609x; 1.5609x over previous
//
#include <hip/hip_runtime.h>
#include <cstdint>
#include <cstddef>

#define T_STEPS 16
#define BB 512
#define NF 1024
#define NI 256
#define NH 2048
#define KSTEPS 5

typedef __bf16 bf16;
typedef __bf16 bf16x8 __attribute__((ext_vector_type(8)));
typedef __bf16 bf16x4 __attribute__((ext_vector_type(4)));
typedef float f32x4 __attribute__((ext_vector_type(4)));

enum { EPI_BF16 = 0, EPI_F32 = 1, EPI_TEMPS = 2, EPI_W1 = 3 };

__device__ __forceinline__ void gload_lds16(const bf16* g, void* l) {
  __builtin_amdgcn_global_load_lds(
      (const __attribute__((address_space(1))) void*)g,
      (__attribute__((address_space(3))) void*)l, 16, 0, 0);
}

// faithful multi-branch prox of w0*|x| + w1*|x - a1|
__device__ __forceinline__ float soft_l1_l1(float z, float w0, float w1, float a1) {
  bool c = (0.0f <= a1);
  float a0s = c ? 0.0f : a1;
  float a1s = c ? a1 : 0.0f;
  float w0s = c ? w0 : w1;
  float w1s = c ? w1 : w0;
  if (z >= a1s + w0s + w1s) return z - w0s - w1s;
  if (z >= a1s + w0s - w1s) return a1s;
  if (z >= a0s + w0s - w1s) return z - w0s + w1s;
  if (z >= a0s - w0s - w1s) return a0s;
  return z + w0s + w1s;
}

// ---------------------------------------------------------------------------
// Batched GEMM: C[m,n] = sum_k Ag[m,k]*Bg[n,k].  128x128 tile, BK=64,
// 4 waves (2x2) each owning a 64x64 sub-tile (16 MFMA : 8 ds_read per kk).
// 2-phase pipeline: issue next-tile global_load_lds before computing current.
// LDS tiles stored [row][64] with chunk-XOR swizzle (chunk ^= row&7) applied
// on the GLOBAL source (G21: gload_lds writes linearly) and on the reads.
// ---------------------------------------------------------------------------
template<int EPI>
__global__ __launch_bounds__(256)
void gemm_bt2(const bf16* __restrict__ Ag, const bf16* __restrict__ Bg,
              int N, int Kd,
              bf16* __restrict__ outb, float* __restrict__ outf,
              bf16* __restrict__ out2, const float* __restrict__ srcf,
              const float* __restrict__ alpha, int inv_alpha)
{
  __shared__ char smem[65536];   // 2 bufs x (A 16KB + B 16KB)
  const int tid = threadIdx.x, lane = tid & 63, wid = tid >> 6;
  const int wr = wid >> 1, wc = wid & 1;
  const int r16 = lane & 15, q16 = lane >> 4;
  const int bm0 = blockIdx.x * 128, bn0 = blockIdx.y * 128;
  const int sw = r16 & 7;

  f32x4 acc[4][4] = {};

  auto stage = [&](int buf, int kt) {
    char* da = smem + buf * 32768;
    char* db = da + 16384;
#pragma unroll
    for (int it = 0; it < 4; ++it) {
      int idx = it * 256 + tid;
      int row = idx >> 3, sc = (idx & 7) ^ (row & 7);
      gload_lds16(Ag + (size_t)(bm0 + row) * Kd + kt + sc * 8, da + idx * 16);
    }
#pragma unroll
    for (int it = 0; it < 4; ++it) {
      int idx = it * 256 + tid;
      int row = idx >> 3, sc = (idx & 7) ^ (row & 7);
      gload_lds16(Bg + (size_t)(bn0 + row) * Kd + kt + sc * 8, db + idx * 16);
    }
  };

  const int NT = Kd >> 6;
  stage(0, 0);
  __syncthreads();
  for (int t = 0; t < NT; ++t) {
    int cur = t & 1;
    if (t + 1 < NT) stage(cur ^ 1, (t + 1) * 64);
    const char* Ab = smem + cur * 32768;
    const char* Bb = Ab + 16384;
#pragma unroll
    for (int kk = 0; kk < 2; ++kk) {
      int ch = ((kk * 4 + q16) ^ sw) * 16;
      bf16x8 af[4], bfr[4];
#pragma unroll
      for (int i = 0; i < 4; ++i)
        af[i] = *(const bf16x8*)(Ab + (wr * 64 + i * 16 + r16) * 128 + ch);
#pragma unroll
      for (int j = 0; j < 4; ++j)
        bfr[j] = *(const bf16x8*)(Bb + (wc * 64 + j * 16 + r16) * 128 + ch);
#pragma unroll
      for (int i = 0; i < 4; ++i)
#pragma unroll
        for (int j = 0; j < 4; ++j)
          acc[i][j] = __builtin_amdgcn_mfma_f32_16x16x32_bf16(af[i], bfr[j], acc[i][j], 0, 0, 0);
    }
    __syncthreads();
  }

  float scale = inv_alpha ? 1.f / alpha[0] : 1.f;
#pragma unroll
  for (int i = 0; i < 4; ++i) {
#pragma unroll
    for (int j = 0; j < 4; ++j) {
#pragma unroll
      for (int e = 0; e < 4; ++e) {
        int m = bm0 + wr * 64 + i * 16 + q16 * 4 + e;
        int n = bn0 + wc * 64 + j * 16 + r16;
        size_t o = (size_t)m * N + n;
        float v = acc[i][j][e] * scale;
        if (EPI == EPI_BF16) {
          outb[o] = (bf16)v;
        } else if (EPI == EPI_F32) {
          outf[o] = v;
        } else if (EPI == EPI_TEMPS) {
          outb[o] = (bf16)v;
          out2[o] = (bf16)((m == n ? 1.f : 0.f) - v);
        } else { // EPI_W1
          outb[o] = (bf16)(srcf[o] - v);
        }
      }
    }
  }
}

// ---------------------------------------------------------------------------
// Scan GEMM: 64x64 tile, BK=128, wave-level K-split: each of the 4 waves
// computes the FULL 64x64 output over its private K=32 slice (wave-tile
// 64x64 -> 16 MFMA : 8 ds_read_b128), then a conflict-free LDS reduce
// (lane stride 76 f32: bank period covers all 32 banks 2-way).
// DUAL: also computes a1 = h@G^T with shared A-fragments (removes the
// standalone a1 GEMM), stores a1 f32, shrinks with in-register a1.
// Epilogue: h_out = soft_l1_l1(acc + xv, w0, w1, a1).
// ---------------------------------------------------------------------------
template<bool DUAL>
__global__ __launch_bounds__(256)
void gemm_scan(const bf16* __restrict__ Ag, const bf16* __restrict__ B1g,
               const bf16* __restrict__ B2g, int N, int Kd,
               const bf16* __restrict__ xv, const float* __restrict__ a1in,
               float* __restrict__ a1out, bf16* __restrict__ outb,
               const float* __restrict__ alpha, const float* __restrict__ lam0,
               const float* __restrict__ lam1)
{
  constexpr int HALF = DUAL ? 49152 : 32768;          // A + B1 (+ B2) per buffer
  constexpr int SMEM = DUAL ? 98304 : 77824;          // >= reduce area 4*64*76*4
  __shared__ char smem[SMEM];
  const int tid = threadIdx.x, lane = tid & 63, wid = tid >> 6;
  const int r16 = lane & 15, q16 = lane >> 4;
  const int bm0 = blockIdx.x * 64, bn0 = blockIdx.y * 64;
  const int sw = r16 & 7;
  const int chbase = ((wid * 4 + q16) ^ sw) * 16;     // wave's K-slice chunk (swizzled)

  f32x4 accW[4][4] = {};
  f32x4 accG[4][4] = {};  // dead-code-eliminated when !DUAL

  auto stage = [&](int buf, int kt) {
    char* base = smem + buf * HALF;
#pragma unroll
    for (int it = 0; it < 4; ++it) {
      int idx = it * 256 + tid;
      int row = idx >> 4, sc = (idx & 15) ^ (row & 7);
      gload_lds16(Ag + (size_t)(bm0 + row) * Kd + kt + sc * 8, base + idx * 16);
    }
#pragma unroll
    for (int it = 0; it < 4; ++it) {
      int idx = it * 256 + tid;
      int row = idx >> 4, sc = (idx & 15) ^ (row & 7);
      gload_lds16(B1g + (size_t)(bn0 + row) * Kd + kt + sc * 8, base + 16384 + idx * 16);
    }
    if constexpr (DUAL) {
#pragma unroll
      for (int it = 0; it < 4; ++it) {
        int idx = it * 256 + tid;
        int row = idx >> 4, sc = (idx & 15) ^ (row & 7);
        gload_lds16(B2g + (size_t)(bn0 + row) * Kd + kt + sc * 8, base + 32768 + idx * 16);
      }
    }
  };

  const int NT = Kd >> 7;
  stage(0, 0);
  __syncthreads();
  for (int t = 0; t < NT; ++t) {
    int cur = t & 1;
    if (t + 1 < NT) stage(cur ^ 1, (t + 1) * 128);
    const char* Ab = smem + cur * HALF;
    const char* B1b = Ab + 16384;
    bf16x8 af[4], b1[4];
#pragma unroll
    for (int i = 0; i < 4; ++i)
      af[i] = *(const bf16x8*)(Ab + (i * 16 + r16) * 256 + chbase);
#pragma unroll
    for (int j = 0; j < 4; ++j)
      b1[j] = *(const bf16x8*)(B1b + (j * 16 + r16) * 256 + chbase);
#pragma unroll
    for (int i = 0; i < 4; ++i)
#pragma unroll
      for (int j = 0; j < 4; ++j)
        accW[i][j] = __builtin_amdgcn_mfma_f32_16x16x32_bf16(af[i], b1[j], accW[i][j], 0, 0, 0);
    if constexpr (DUAL) {
      const char* B2b = Ab + 32768;
      bf16x8 b2[4];
#pragma unroll
      for (int j = 0; j < 4; ++j)
        b2[j] = *(const bf16x8*)(B2b + (j * 16 + r16) * 256 + chbase);
#pragma unroll
      for (int i = 0; i < 4; ++i)
#pragma unroll
        for (int j = 0; j < 4; ++j)
          accG[i][j] = __builtin_amdgcn_mfma_f32_16x16x32_bf16(af[i], b2[j], accG[i][j], 0, 0, 0);
    }
    __syncthreads();
  }

  // cross-wave K-reduce via LDS (aliases staging; K-loop fully drained above)
  float* red = (float*)smem;
  const int myrow = (wid * 64 + lane) * 76;
  const int lrow = lane * 76;
  f32x4 sg[4];
  if constexpr (DUAL) {
#pragma unroll
    for (int i = 0; i < 4; ++i)
#pragma unroll
      for (int j = 0; j < 4; ++j)
        *(f32x4*)&red[myrow + (i * 4 + j) * 4] = accG[i][j];
    __syncthreads();
#pragma unroll
    for (int j = 0; j < 4; ++j) {
      sg[j] = *(const f32x4*)&red[lrow + wid * 16 + j * 4];
#pragma unroll
      for (int w = 1; w < 4; ++w)
        sg[j] += *(const f32x4*)&red[w * 4864 + lrow + wid * 16 + j * 4];
    }
    __syncthreads();
  }
#pragma unroll
  for (int i = 0; i < 4; ++i)
#pragma unroll
    for (int j = 0; j < 4; ++j)
      *(f32x4*)&red[myrow + (i * 4 + j) * 4] = accW[i][j];
  __syncthreads();
  f32x4 sz[4];
#pragma unroll
  for (int j = 0; j < 4; ++j) {
    sz[j] = *(const f32x4*)&red[lrow + wid * 16 + j * 4];
#pragma unroll
    for (int w = 1; w < 4; ++w)
      sz[j] += *(const f32x4*)&red[w * 4864 + lrow + wid * 16 + j * 4];
  }

  float al = alpha[0];
  float w0 = lam0[0] / al, w1 = lam1[0] / al;
#pragma unroll
  for (int j = 0; j < 4; ++j) {
#pragma unroll
    for (int e = 0; e < 4; ++e) {
      int m = bm0 + wid * 16 + q16 * 4 + e;   // wave wid reduced frag-row i == wid
      int n = bn0 + j * 16 + r16;
      size_t o = (size_t)m * N + n;
      float a1v;
      if constexpr (DUAL) { a1v = sg[j][e]; a1out[o] = a1v; }
      else                { a1v = a1in[o]; }
      float z = sz[j][e] + (float)xv[o];
      outb[o] = (bf16)soft_l1_l1(z, w0, w1, a1v);
    }
  }
}

__global__ void cast_f32_bf16(const float* __restrict__ in, bf16* __restrict__ out, int n) {
  int i = (blockIdx.x * blockDim.x + threadIdx.x) * 4;
  if (i + 4 <= n) {
    float4 v = *(const float4*)&in[i];
    bf16x4 p;
    p[0] = (bf16)v.x; p[1] = (bf16)v.y; p[2] = (bf16)v.z; p[3] = (bf16)v.w;
    *(bf16x4*)&out[i] = p;
  } else {
    for (; i < n; ++i) out[i] = (bf16)in[i];
  }
}

// out[c,r] = (bf16) in[r,c];  in: [R,C] f32 row-major -> out: [C,R] bf16 row-major
__global__ void transpose_cast(const float* __restrict__ in, bf16* __restrict__ out, int R, int C) {
  __shared__ float tile[32][33];
  int bx = blockIdx.x * 32, by = blockIdx.y * 32;
  int tx = threadIdx.x, ty = threadIdx.y;
  for (int i = ty; i < 32; i += 8) {
    int r = by + i, c = bx + tx;
    if (r < R && c < C) tile[i][tx] = in[(size_t)r * C + c];
  }
  __syncthreads();
  for (int i = ty; i < 32; i += 8) {
    int r = bx + i, c = by + tx;
    if (r < C && c < R) out[(size_t)r * R + c] = (bf16)tile[tx][i];
  }
}

extern "C" void kernel_launch(void* const* d_in, const int* in_sizes, int n_in,
                              void* d_out, int out_size, void* d_ws, size_t ws_size,
                              hipStream_t stream) {
  // inputs: 0 pre_input (unused), 1 raw, 2 A, 3 D, 4 G, 5 h_0,
  //         6 alpha, 7 lambda0, 8 lambda1, 9 K (fixed = 5)
  const float* rawf = (const float*)d_in[1];
  const float* Af   = (const float*)d_in[2];
  const float* Df   = (const float*)d_in[3];
  const float* Gf   = (const float*)d_in[4];
  const float* h0f  = (const float*)d_in[5];
  const float* alp  = (const float*)d_in[6];
  const float* l0   = (const float*)d_in[7];
  const float* l1   = (const float*)d_in[8];
  float* outp = (float*)d_out;

  char* w = (char*)d_ws;
  auto allocb = [&](size_t bytes) { char* p = w; w += (bytes + 255) & ~(size_t)255; return p; };
  bf16* Abf  = (bf16*)allocb((size_t)NI * NF * 2);
  bf16* At   = (bf16*)allocb((size_t)NF * NI * 2);
  bf16* Dbf  = (bf16*)allocb((size_t)NF * NH * 2);
  bf16* Dt   = (bf16*)allocb((size_t)NH * NF * 2);
  bf16* Gt   = (bf16*)allocb((size_t)NH * NH * 2);
  bf16* rawb = (bf16*)allocb((size_t)T_STEPS * BB * NF * 2);
  bf16* AtA  = (bf16*)allocb((size_t)NF * NF * 2);
  bf16* Vm   = (bf16*)allocb((size_t)NH * NI * 2);
  bf16* M3t  = (bf16*)allocb((size_t)NH * NF * 2);
  bf16* tmpb = (bf16*)allocb((size_t)NH * NH * 2);
  bf16* Sm   = (bf16*)allocb((size_t)NH * NH * 2);
  bf16* W1m  = (bf16*)allocb((size_t)NH * NH * 2);
  bf16* X    = (bf16*)allocb((size_t)T_STEPS * BB * NI * 2);
  float* A1f = (float*)allocb((size_t)BB * NH * 4);
  bf16* H0   = (bf16*)allocb((size_t)BB * NH * 2);
  bf16* Hb0  = (bf16*)allocb((size_t)BB * NH * 2);
  bf16* Hb1  = (bf16*)allocb((size_t)BB * NH * 2);
  bf16* HS   = (bf16*)allocb((size_t)T_STEPS * BB * NH * 2);
  // XV (T*B x NH bf16 = 32 MB) lives in d_out: fully written before use, dead
  // before the final projection overwrites d_out.
  bf16* XV   = (bf16*)d_out;

  auto cgrid = [](int n) { return dim3((unsigned)((n / 4 + 255) / 256)); };
  cast_f32_bf16<<<cgrid(NI * NF), 256, 0, stream>>>(Af, Abf, NI * NF);
  cast_f32_bf16<<<cgrid(NF * NH), 256, 0, stream>>>(Df, Dbf, NF * NH);
  cast_f32_bf16<<<cgrid(T_STEPS * BB * NF), 256, 0, stream>>>(rawf, rawb, T_STEPS * BB * NF);
  cast_f32_bf16<<<cgrid(BB * NH), 256, 0, stream>>>(h0f, H0, BB * NH);
  transpose_cast<<<dim3(NF / 32, NI / 32), dim3(32, 8), 0, stream>>>(Af, At, NI, NF);
  transpose_cast<<<dim3(NH / 32, NF / 32), dim3(32, 8), 0, stream>>>(Df, Dt, NF, NH);
  transpose_cast<<<dim3(NH / 32, NH / 32), dim3(32, 8), 0, stream>>>(Gf, Gt, NH, NH);

  // AtA[f1,f2] = sum_i A[i,f1]A[i,f2]
  gemm_bt2<EPI_BF16><<<dim3(NF / 128, NF / 128), 256, 0, stream>>>(
      At, At, NF, NI, AtA, nullptr, nullptr, nullptr, alp, 0);
  // V[h,i] = (1/al) sum_f D[f,h]A[i,f]
  gemm_bt2<EPI_BF16><<<dim3(NH / 128, NI / 128), 256, 0, stream>>>(
      Dt, Abf, NI, NF, Vm, nullptr, nullptr, nullptr, alp, 1);
  // M3t[h,f] = sum_f2 Dt[h,f2]AtA[f,f2] = (AtA@D)[f,h]  (AtA symmetric)
  gemm_bt2<EPI_BF16><<<dim3(NH / 128, NF / 128), 256, 0, stream>>>(
      Dt, AtA, NF, NF, M3t, nullptr, nullptr, nullptr, alp, 0);
  // temp = (1/al) D^T (AtA D); S = I - temp (dual store)
  gemm_bt2<EPI_TEMPS><<<dim3(NH / 128, NH / 128), 256, 0, stream>>>(
      Dt, M3t, NH, NF, tmpb, nullptr, Sm, nullptr, alp, 1);
  // W1 = G - temp@G
  gemm_bt2<EPI_W1><<<dim3(NH / 128, NH / 128), 256, 0, stream>>>(
      tmpb, Gt, NH, NH, W1m, nullptr, nullptr, Gf, alp, 0);
  // X = raw @ A^T
  gemm_bt2<EPI_BF16><<<dim3(T_STEPS * BB / 128, NI / 128), 256, 0, stream>>>(
      rawb, Abf, NI, NF, X, nullptr, nullptr, nullptr, alp, 0);
  // XV = X @ V^T
  gemm_bt2<EPI_BF16><<<dim3(T_STEPS * BB / 128, NH / 128), 256, 0, stream>>>(
      X, Vm, NH, NI, XV, nullptr, nullptr, nullptr, alp, 0);

  const size_t HBsz = (size_t)BB * NH;
  const bf16* hp = H0;
  for (int t = 0; t < T_STEPS; ++t) {
    const bf16* xvt = XV + (size_t)t * HBsz;
    bf16* dsts[KSTEPS];
    for (int k = 0; k < KSTEPS; ++k) dsts[k] = (k & 1) ? Hb1 : Hb0;
    dsts[KSTEPS - 1] = HS + (size_t)t * HBsz;
    // k=0: h = shrink(h@W1^T + xv, a1 = h@G) — a1 fused (dual-B), stored f32
    gemm_scan<true><<<dim3(BB / 64, NH / 64), 256, 0, stream>>>(
        hp, W1m, Gt, NH, NH, xvt, nullptr, A1f, dsts[0], alp, l0, l1);
    const bf16* cur = dsts[0];
    for (int k = 1; k < KSTEPS; ++k) {
      // h = shrink(xv + h@S^T)
      gemm_scan<false><<<dim3(BB / 64, NH / 64), 256, 0, stream>>>(
          cur, Sm, nullptr, NH, NH, xvt, A1f, nullptr, dsts[k], alp, l0, l1);
      cur = dsts[k];
    }
    hp = HS + (size_t)t * HBsz;
  }
  // z_hat = HS @ D^T (fp32 direct to d_out)
  gemm_bt2<EPI_F32><<<dim3(T_STEPS * BB / 128, NF / 128), 256, 0, stream>>>(
      HS, Dbf, NF, NH, nullptr, outp, nullptr, nullptr, alp, 0);
}

// Round 3
// 1790.697 us; speedup vs baseline: 1.6799x; 1.0762x over previous
//
#include <hip/hip_runtime.h>
#include <cstdint>
#include <cstddef>

#define T_STEPS 16
#define BB 512
#define NF 1024
#define NI 256
#define NH 2048
#define KSTEPS 5

typedef __bf16 bf16;
typedef __bf16 bf16x8 __attribute__((ext_vector_type(8)));
typedef __bf16 bf16x4 __attribute__((ext_vector_type(4)));
typedef float f32x4 __attribute__((ext_vector_type(4)));

enum { EPI_BF16 = 0, EPI_F32 = 1, EPI_TEMPS = 2, EPI_W1 = 3 };

__device__ __forceinline__ void gload_lds16(const bf16* g, void* l) {
  __builtin_amdgcn_global_load_lds(
      (const __attribute__((address_space(1))) void*)g,
      (__attribute__((address_space(3))) void*)l, 16, 0, 0);
}

// faithful multi-branch prox of w0*|x| + w1*|x - a1|
__device__ __forceinline__ float soft_l1_l1(float z, float w0, float w1, float a1) {
  bool c = (0.0f <= a1);
  float a0s = c ? 0.0f : a1;
  float a1s = c ? a1 : 0.0f;
  float w0s = c ? w0 : w1;
  float w1s = c ? w1 : w0;
  if (z >= a1s + w0s + w1s) return z - w0s - w1s;
  if (z >= a1s + w0s - w1s) return a1s;
  if (z >= a0s + w0s - w1s) return z - w0s + w1s;
  if (z >= a0s - w0s - w1s) return a0s;
  return z + w0s + w1s;
}

// ---------------------------------------------------------------------------
// Batched GEMM: C[m,n] = sum_k Ag[m,k]*Bg[n,k].  128x128 tile, BK=64,
// 4 waves (2x2) each owning a 64x64 sub-tile. 4-deep LDS pipeline with
// COUNTED s_waitcnt vmcnt(24) + raw s_barrier (T3/T4): loads stay in flight
// across barriers; never drained to 0 in the main loop.
// Chunk-XOR swizzle (chunk ^= row&7) applied on the GLOBAL source (G21) and
// on the LDS reads.
// ---------------------------------------------------------------------------
template<int EPI>
__global__ __launch_bounds__(256)
void gemm_bt2(const bf16* __restrict__ Ag, const bf16* __restrict__ Bg,
              int N, int Kd,
              bf16* __restrict__ outb, float* __restrict__ outf,
              bf16* __restrict__ out2, const float* __restrict__ srcf,
              const float* __restrict__ alpha, int inv_alpha)
{
  __shared__ char smem[131072];   // 4 bufs x (A 16KB + B 16KB)
  const int tid = threadIdx.x, lane = tid & 63, wid = tid >> 6;
  const int wr = wid >> 1, wc = wid & 1;
  const int r16 = lane & 15, q16 = lane >> 4;
  const int bm0 = blockIdx.x * 128, bn0 = blockIdx.y * 128;
  const int sw = r16 & 7;

  f32x4 acc[4][4] = {};

  auto stage = [&](int buf, int kt) {
    char* da = smem + buf * 32768;
    char* db = da + 16384;
#pragma unroll
    for (int it = 0; it < 4; ++it) {
      int idx = it * 256 + tid;
      int row = idx >> 3, sc = (idx & 7) ^ (row & 7);
      gload_lds16(Ag + (size_t)(bm0 + row) * Kd + kt + sc * 8, da + idx * 16);
    }
#pragma unroll
    for (int it = 0; it < 4; ++it) {
      int idx = it * 256 + tid;
      int row = idx >> 3, sc = (idx & 7) ^ (row & 7);
      gload_lds16(Bg + (size_t)(bn0 + row) * Kd + kt + sc * 8, db + idx * 16);
    }
  };

  auto compute = [&](int buf) {
    const char* Ab = smem + buf * 32768;
    const char* Bb = Ab + 16384;
#pragma unroll
    for (int kk = 0; kk < 2; ++kk) {
      int ch = ((kk * 4 + q16) ^ sw) * 16;
      bf16x8 af[4], bfr[4];
#pragma unroll
      for (int i = 0; i < 4; ++i)
        af[i] = *(const bf16x8*)(Ab + (wr * 64 + i * 16 + r16) * 128 + ch);
#pragma unroll
      for (int j = 0; j < 4; ++j)
        bfr[j] = *(const bf16x8*)(Bb + (wc * 64 + j * 16 + r16) * 128 + ch);
#pragma unroll
      for (int i = 0; i < 4; ++i)
#pragma unroll
        for (int j = 0; j < 4; ++j)
          acc[i][j] = __builtin_amdgcn_mfma_f32_16x16x32_bf16(af[i], bfr[j], acc[i][j], 0, 0, 0);
    }
  };

  const int NT = Kd >> 6;           // Kd in {256,1024,2048} -> NT in {4,16,32}
  for (int p = 0; p < 3; ++p) stage(p, p * 64);
  int sbuf = 3, cbuf = 0, t = 0;
  for (; t < NT - 3; ++t) {
    stage(sbuf, (t + 3) * 64);
    sbuf = (sbuf + 1 == 4) ? 0 : sbuf + 1;
    asm volatile("s_waitcnt vmcnt(24)" ::: "memory");
    __builtin_amdgcn_s_barrier();
    __builtin_amdgcn_sched_barrier(0);
    compute(cbuf);
    __builtin_amdgcn_sched_barrier(0);
    __builtin_amdgcn_s_barrier();
    cbuf = (cbuf + 1 == 4) ? 0 : cbuf + 1;
  }
  asm volatile("s_waitcnt vmcnt(0)" ::: "memory");
  __builtin_amdgcn_s_barrier();
  __builtin_amdgcn_sched_barrier(0);
  for (; t < NT; ++t) {
    compute(cbuf);
    cbuf = (cbuf + 1 == 4) ? 0 : cbuf + 1;
  }

  float scale = inv_alpha ? 1.f / alpha[0] : 1.f;
#pragma unroll
  for (int i = 0; i < 4; ++i) {
#pragma unroll
    for (int j = 0; j < 4; ++j) {
#pragma unroll
      for (int e = 0; e < 4; ++e) {
        int m = bm0 + wr * 64 + i * 16 + q16 * 4 + e;
        int n = bn0 + wc * 64 + j * 16 + r16;
        size_t o = (size_t)m * N + n;
        float v = acc[i][j][e] * scale;
        if (EPI == EPI_BF16) {
          outb[o] = (bf16)v;
        } else if (EPI == EPI_F32) {
          outf[o] = v;
        } else if (EPI == EPI_TEMPS) {
          outb[o] = (bf16)v;
          out2[o] = (bf16)((m == n ? 1.f : 0.f) - v);
        } else { // EPI_W1
          outb[o] = (bf16)(srcf[o] - v);
        }
      }
    }
  }
}

// ---------------------------------------------------------------------------
// Scan GEMM: 64x64 tile, BK=128, wave-level K-split (each wave: full 64x64
// over its private K=32 slice; 16 MFMA : 8 ds_read per tile), LDS cross-wave
// reduce at the end. Pipeline: DEPTH=4 (plain, 128KB) / DEPTH=3 (DUAL,
// 144KB) with counted vmcnt(24) + raw barriers.
// DUAL: also computes a1 = h@G^T sharing A-fragments; stores a1 f32.
// Epilogue: h_out = soft_l1_l1(acc + xv, w0, w1, a1).
// ---------------------------------------------------------------------------
template<bool DUAL>
__global__ __launch_bounds__(256)
void gemm_scan(const bf16* __restrict__ Ag, const bf16* __restrict__ B1g,
               const bf16* __restrict__ B2g, int N, int Kd,
               const bf16* __restrict__ xv, const float* __restrict__ a1in,
               float* __restrict__ a1out, bf16* __restrict__ outb,
               const float* __restrict__ alpha, const float* __restrict__ lam0,
               const float* __restrict__ lam1)
{
  constexpr int HALF = DUAL ? 49152 : 32768;   // per-buffer bytes
  constexpr int D = DUAL ? 3 : 4;
  constexpr int SMEM = HALF * D;               // 147456 / 131072; >= reduce 77824
  __shared__ char smem[SMEM];
  const int tid = threadIdx.x, lane = tid & 63, wid = tid >> 6;
  const int r16 = lane & 15, q16 = lane >> 4;
  const int bm0 = blockIdx.x * 64, bn0 = blockIdx.y * 64;
  const int sw = r16 & 7;
  const int chbase = ((wid * 4 + q16) ^ sw) * 16;   // wave's K-slice chunk (swizzled)

  f32x4 accW[4][4] = {};
  f32x4 accG[4][4] = {};   // DCE'd when !DUAL

  auto stage = [&](int buf, int kt) {
    char* base = smem + buf * HALF;
#pragma unroll
    for (int it = 0; it < 4; ++it) {
      int idx = it * 256 + tid;
      int row = idx >> 4, sc = (idx & 15) ^ (row & 7);
      gload_lds16(Ag + (size_t)(bm0 + row) * Kd + kt + sc * 8, base + idx * 16);
    }
#pragma unroll
    for (int it = 0; it < 4; ++it) {
      int idx = it * 256 + tid;
      int row = idx >> 4, sc = (idx & 15) ^ (row & 7);
      gload_lds16(B1g + (size_t)(bn0 + row) * Kd + kt + sc * 8, base + 16384 + idx * 16);
    }
    if constexpr (DUAL) {
#pragma unroll
      for (int it = 0; it < 4; ++it) {
        int idx = it * 256 + tid;
        int row = idx >> 4, sc = (idx & 15) ^ (row & 7);
        gload_lds16(B2g + (size_t)(bn0 + row) * Kd + kt + sc * 8, base + 32768 + idx * 16);
      }
    }
  };

  auto compute = [&](int buf) {
    const char* Ab = smem + buf * HALF;
    const char* B1b = Ab + 16384;
    bf16x8 af[4], b1[4];
#pragma unroll
    for (int i = 0; i < 4; ++i)
      af[i] = *(const bf16x8*)(Ab + (i * 16 + r16) * 256 + chbase);
#pragma unroll
    for (int j = 0; j < 4; ++j)
      b1[j] = *(const bf16x8*)(B1b + (j * 16 + r16) * 256 + chbase);
#pragma unroll
    for (int i = 0; i < 4; ++i)
#pragma unroll
      for (int j = 0; j < 4; ++j)
        accW[i][j] = __builtin_amdgcn_mfma_f32_16x16x32_bf16(af[i], b1[j], accW[i][j], 0, 0, 0);
    if constexpr (DUAL) {
      const char* B2b = Ab + 32768;
      bf16x8 b2[4];
#pragma unroll
      for (int j = 0; j < 4; ++j)
        b2[j] = *(const bf16x8*)(B2b + (j * 16 + r16) * 256 + chbase);
#pragma unroll
      for (int i = 0; i < 4; ++i)
#pragma unroll
        for (int j = 0; j < 4; ++j)
          accG[i][j] = __builtin_amdgcn_mfma_f32_16x16x32_bf16(af[i], b2[j], accG[i][j], 0, 0, 0);
    }
  };

  const int NT = Kd >> 7;   // 16
  for (int p = 0; p < D - 1; ++p) stage(p, p * 128);
  int sbuf = D - 1, cbuf = 0, t = 0;
  for (; t < NT - (D - 1); ++t) {
    stage(sbuf, (t + D - 1) * 128);
    sbuf = (sbuf + 1 == D) ? 0 : sbuf + 1;
    asm volatile("s_waitcnt vmcnt(24)" ::: "memory");
    __builtin_amdgcn_s_barrier();
    __builtin_amdgcn_sched_barrier(0);
    compute(cbuf);
    __builtin_amdgcn_sched_barrier(0);
    __builtin_amdgcn_s_barrier();
    cbuf = (cbuf + 1 == D) ? 0 : cbuf + 1;
  }
  asm volatile("s_waitcnt vmcnt(0)" ::: "memory");
  __builtin_amdgcn_s_barrier();
  __builtin_amdgcn_sched_barrier(0);
  for (; t < NT; ++t) {
    compute(cbuf);
    cbuf = (cbuf + 1 == D) ? 0 : cbuf + 1;
  }
  __syncthreads();

  // cross-wave K-reduce via LDS (aliases staging; all loads drained above)
  float* red = (float*)smem;
  const int myrow = (wid * 64 + lane) * 76;
  const int lrow = lane * 76;
  f32x4 sg[4];
  if constexpr (DUAL) {
#pragma unroll
    for (int i = 0; i < 4; ++i)
#pragma unroll
      for (int j = 0; j < 4; ++j)
        *(f32x4*)&red[myrow + (i * 4 + j) * 4] = accG[i][j];
    __syncthreads();
#pragma unroll
    for (int j = 0; j < 4; ++j) {
      sg[j] = *(const f32x4*)&red[lrow + wid * 16 + j * 4];
#pragma unroll
      for (int w = 1; w < 4; ++w)
        sg[j] += *(const f32x4*)&red[w * 4864 + lrow + wid * 16 + j * 4];
    }
    __syncthreads();
  }
#pragma unroll
  for (int i = 0; i < 4; ++i)
#pragma unroll
    for (int j = 0; j < 4; ++j)
      *(f32x4*)&red[myrow + (i * 4 + j) * 4] = accW[i][j];
  __syncthreads();
  f32x4 sz[4];
#pragma unroll
  for (int j = 0; j < 4; ++j) {
    sz[j] = *(const f32x4*)&red[lrow + wid * 16 + j * 4];
#pragma unroll
    for (int w = 1; w < 4; ++w)
      sz[j] += *(const f32x4*)&red[w * 4864 + lrow + wid * 16 + j * 4];
  }

  float al = alpha[0];
  float w0 = lam0[0] / al, w1 = lam1[0] / al;
#pragma unroll
  for (int j = 0; j < 4; ++j) {
#pragma unroll
    for (int e = 0; e < 4; ++e) {
      int m = bm0 + wid * 16 + q16 * 4 + e;   // wave wid reduced frag-row i == wid
      int n = bn0 + j * 16 + r16;
      size_t o = (size_t)m * N + n;
      float a1v;
      if constexpr (DUAL) { a1v = sg[j][e]; a1out[o] = a1v; }
      else                { a1v = a1in[o]; }
      float z = sz[j][e] + (float)xv[o];
      outb[o] = (bf16)soft_l1_l1(z, w0, w1, a1v);
    }
  }
}

__global__ void cast_f32_bf16(const float* __restrict__ in, bf16* __restrict__ out, int n) {
  int i = (blockIdx.x * blockDim.x + threadIdx.x) * 4;
  if (i + 4 <= n) {
    float4 v = *(const float4*)&in[i];
    bf16x4 p;
    p[0] = (bf16)v.x; p[1] = (bf16)v.y; p[2] = (bf16)v.z; p[3] = (bf16)v.w;
    *(bf16x4*)&out[i] = p;
  } else {
    for (; i < n; ++i) out[i] = (bf16)in[i];
  }
}

// out[c,r] = (bf16) in[r,c];  in: [R,C] f32 row-major -> out: [C,R] bf16 row-major
__global__ void transpose_cast(const float* __restrict__ in, bf16* __restrict__ out, int R, int C) {
  __shared__ float tile[32][33];
  int bx = blockIdx.x * 32, by = blockIdx.y * 32;
  int tx = threadIdx.x, ty = threadIdx.y;
  for (int i = ty; i < 32; i += 8) {
    int r = by + i, c = bx + tx;
    if (r < R && c < C) tile[i][tx] = in[(size_t)r * C + c];
  }
  __syncthreads();
  for (int i = ty; i < 32; i += 8) {
    int r = bx + i, c = by + tx;
    if (r < C && c < R) out[(size_t)r * R + c] = (bf16)tile[tx][i];
  }
}

extern "C" void kernel_launch(void* const* d_in, const int* in_sizes, int n_in,
                              void* d_out, int out_size, void* d_ws, size_t ws_size,
                              hipStream_t stream) {
  // inputs: 0 pre_input (unused), 1 raw, 2 A, 3 D, 4 G, 5 h_0,
  //         6 alpha, 7 lambda0, 8 lambda1, 9 K (fixed = 5)
  const float* rawf = (const float*)d_in[1];
  const float* Af   = (const float*)d_in[2];
  const float* Df   = (const float*)d_in[3];
  const float* Gf   = (const float*)d_in[4];
  const float* h0f  = (const float*)d_in[5];
  const float* alp  = (const float*)d_in[6];
  const float* l0   = (const float*)d_in[7];
  const float* l1   = (const float*)d_in[8];
  float* outp = (float*)d_out;

  char* w = (char*)d_ws;
  auto allocb = [&](size_t bytes) { char* p = w; w += (bytes + 255) & ~(size_t)255; return p; };
  bf16* Abf  = (bf16*)allocb((size_t)NI * NF * 2);
  bf16* At   = (bf16*)allocb((size_t)NF * NI * 2);
  bf16* Dbf  = (bf16*)allocb((size_t)NF * NH * 2);
  bf16* Dt   = (bf16*)allocb((size_t)NH * NF * 2);
  bf16* Gt   = (bf16*)allocb((size_t)NH * NH * 2);
  bf16* rawb = (bf16*)allocb((size_t)T_STEPS * BB * NF * 2);
  bf16* AtA  = (bf16*)allocb((size_t)NF * NF * 2);
  bf16* Vm   = (bf16*)allocb((size_t)NH * NI * 2);
  bf16* M3t  = (bf16*)allocb((size_t)NH * NF * 2);
  bf16* tmpb = (bf16*)allocb((size_t)NH * NH * 2);
  bf16* Sm   = (bf16*)allocb((size_t)NH * NH * 2);
  bf16* W1m  = (bf16*)allocb((size_t)NH * NH * 2);
  bf16* X    = (bf16*)allocb((size_t)T_STEPS * BB * NI * 2);
  float* A1f = (float*)allocb((size_t)BB * NH * 4);
  bf16* H0   = (bf16*)allocb((size_t)BB * NH * 2);
  bf16* Hb0  = (bf16*)allocb((size_t)BB * NH * 2);
  bf16* Hb1  = (bf16*)allocb((size_t)BB * NH * 2);
  bf16* HS   = (bf16*)allocb((size_t)T_STEPS * BB * NH * 2);
  // XV (T*B x NH bf16 = 32 MB) lives in d_out: fully written before use, dead
  // before the final projection overwrites d_out.
  bf16* XV   = (bf16*)d_out;

  auto cgrid = [](int n) { return dim3((unsigned)((n / 4 + 255) / 256)); };
  cast_f32_bf16<<<cgrid(NI * NF), 256, 0, stream>>>(Af, Abf, NI * NF);
  cast_f32_bf16<<<cgrid(NF * NH), 256, 0, stream>>>(Df, Dbf, NF * NH);
  cast_f32_bf16<<<cgrid(T_STEPS * BB * NF), 256, 0, stream>>>(rawf, rawb, T_STEPS * BB * NF);
  cast_f32_bf16<<<cgrid(BB * NH), 256, 0, stream>>>(h0f, H0, BB * NH);
  transpose_cast<<<dim3(NF / 32, NI / 32), dim3(32, 8), 0, stream>>>(Af, At, NI, NF);
  transpose_cast<<<dim3(NH / 32, NF / 32), dim3(32, 8), 0, stream>>>(Df, Dt, NF, NH);
  transpose_cast<<<dim3(NH / 32, NH / 32), dim3(32, 8), 0, stream>>>(Gf, Gt, NH, NH);

  // AtA[f1,f2] = sum_i A[i,f1]A[i,f2]
  gemm_bt2<EPI_BF16><<<dim3(NF / 128, NF / 128), 256, 0, stream>>>(
      At, At, NF, NI, AtA, nullptr, nullptr, nullptr, alp, 0);
  // V[h,i] = (1/al) sum_f D[f,h]A[i,f]
  gemm_bt2<EPI_BF16><<<dim3(NH / 128, NI / 128), 256, 0, stream>>>(
      Dt, Abf, NI, NF, Vm, nullptr, nullptr, nullptr, alp, 1);
  // M3t[h,f] = sum_f2 Dt[h,f2]AtA[f,f2] = (AtA@D)[f,h]  (AtA symmetric)
  gemm_bt2<EPI_BF16><<<dim3(NH / 128, NF / 128), 256, 0, stream>>>(
      Dt, AtA, NF, NF, M3t, nullptr, nullptr, nullptr, alp, 0);
  // temp = (1/al) D^T (AtA D); S = I - temp (dual store)
  gemm_bt2<EPI_TEMPS><<<dim3(NH / 128, NH / 128), 256, 0, stream>>>(
      Dt, M3t, NH, NF, tmpb, nullptr, Sm, nullptr, alp, 1);
  // W1 = G - temp@G
  gemm_bt2<EPI_W1><<<dim3(NH / 128, NH / 128), 256, 0, stream>>>(
      tmpb, Gt, NH, NH, W1m, nullptr, nullptr, Gf, alp, 0);
  // X = raw @ A^T
  gemm_bt2<EPI_BF16><<<dim3(T_STEPS * BB / 128, NI / 128), 256, 0, stream>>>(
      rawb, Abf, NI, NF, X, nullptr, nullptr, nullptr, alp, 0);
  // XV = X @ V^T
  gemm_bt2<EPI_BF16><<<dim3(T_STEPS * BB / 128, NH / 128), 256, 0, stream>>>(
      X, Vm, NH, NI, XV, nullptr, nullptr, nullptr, alp, 0);

  const size_t HBsz = (size_t)BB * NH;
  const bf16* hp = H0;
  for (int t = 0; t < T_STEPS; ++t) {
    const bf16* xvt = XV + (size_t)t * HBsz;
    bf16* dsts[KSTEPS];
    for (int k = 0; k < KSTEPS; ++k) dsts[k] = (k & 1) ? Hb1 : Hb0;
    dsts[KSTEPS - 1] = HS + (size_t)t * HBsz;
    // k=0: h = shrink(h@W1^T + xv, a1 = h@G) — a1 fused (dual-B), stored f32
    gemm_scan<true><<<dim3(BB / 64, NH / 64), 256, 0, stream>>>(
        hp, W1m, Gt, NH, NH, xvt, nullptr, A1f, dsts[0], alp, l0, l1);
    const bf16* cur = dsts[0];
    for (int k = 1; k < KSTEPS; ++k) {
      // h = shrink(xv + h@S^T)
      gemm_scan<false><<<dim3(BB / 64, NH / 64), 256, 0, stream>>>(
          cur, Sm, nullptr, NH, NH, xvt, A1f, nullptr, dsts[k], alp, l0, l1);
      cur = dsts[k];
    }
    hp = HS + (size_t)t * HBsz;
  }
  // z_hat = HS @ D^T (fp32 direct to d_out)
  gemm_bt2<EPI_F32><<<dim3(T_STEPS * BB / 128, NF / 128), 256, 0, stream>>>(
      HS, Dbf, NF, NH, nullptr, outp, nullptr, nullptr, alp, 0);
}

// Round 4
// 1637.419 us; speedup vs baseline: 1.8371x; 1.0936x over previous
//
#include <hip/hip_runtime.h>
#include <cstdint>
#include <cstddef>

#define T_STEPS 16
#define BB 512
#define NF 1024
#define NI 256
#define NH 2048
#define KSTEPS 5

typedef __bf16 bf16;
typedef __bf16 bf16x8 __attribute__((ext_vector_type(8)));
typedef __bf16 bf16x4 __attribute__((ext_vector_type(4)));
typedef float f32x4 __attribute__((ext_vector_type(4)));

enum { EPI_BF16 = 0, EPI_F32 = 1, EPI_TEMPS = 2, EPI_W1 = 3 };

__device__ __forceinline__ void gload_lds16(const bf16* g, void* l) {
  __builtin_amdgcn_global_load_lds(
      (const __attribute__((address_space(1))) void*)g,
      (__attribute__((address_space(3))) void*)l, 16, 0, 0);
}

// faithful multi-branch prox of w0*|x| + w1*|x - a1|
__device__ __forceinline__ float soft_l1_l1(float z, float w0, float w1, float a1) {
  bool c = (0.0f <= a1);
  float a0s = c ? 0.0f : a1;
  float a1s = c ? a1 : 0.0f;
  float w0s = c ? w0 : w1;
  float w1s = c ? w1 : w0;
  if (z >= a1s + w0s + w1s) return z - w0s - w1s;
  if (z >= a1s + w0s - w1s) return a1s;
  if (z >= a0s + w0s - w1s) return z - w0s + w1s;
  if (z >= a0s - w0s - w1s) return a0s;
  return z + w0s + w1s;
}

// ---------------------------------------------------------------------------
// Batched GEMM: C[m,n] = sum_k Ag[m,k]*Bg[n,k].  128x128 tile, BK=64,
// 4 waves (2x2) each owning a 64x64 sub-tile.
// D=2 buffers (64KB LDS -> 2 blocks/CU) with COUNTED s_waitcnt vmcnt(8) +
// raw s_barrier: next-tile loads stay in flight across barriers.
// 1-D grid + XCD chunk-swizzle: wg = (bid%8)*(total/8)+bid/8 (total%8==0).
// Chunk-XOR swizzle (chunk ^= row&7) on the GLOBAL source (G21) and reads.
// ---------------------------------------------------------------------------
template<int EPI>
__global__ __launch_bounds__(256)
void gemm_bt2(const bf16* __restrict__ Ag, const bf16* __restrict__ Bg,
              int N, int Kd, int nbx, int total,
              bf16* __restrict__ outb, float* __restrict__ outf,
              bf16* __restrict__ out2, const float* __restrict__ srcf,
              const float* __restrict__ alpha, int inv_alpha)
{
  __shared__ char smem[65536];   // 2 bufs x (A 16KB + B 16KB)
  const int tid = threadIdx.x, lane = tid & 63, wid = tid >> 6;
  const int wr = wid >> 1, wc = wid & 1;
  const int r16 = lane & 15, q16 = lane >> 4;
  const int bid = blockIdx.x;
  const int wg = (bid & 7) * (total >> 3) + (bid >> 3);
  const int bm0 = (wg % nbx) * 128, bn0 = (wg / nbx) * 128;
  const int sw = r16 & 7;

  f32x4 acc[4][4] = {};

  auto stage = [&](int buf, int kt) {
    char* da = smem + buf * 32768;
    char* db = da + 16384;
#pragma unroll
    for (int it = 0; it < 4; ++it) {
      int idx = it * 256 + tid;
      int row = idx >> 3, sc = (idx & 7) ^ (row & 7);
      gload_lds16(Ag + (size_t)(bm0 + row) * Kd + kt + sc * 8, da + idx * 16);
    }
#pragma unroll
    for (int it = 0; it < 4; ++it) {
      int idx = it * 256 + tid;
      int row = idx >> 3, sc = (idx & 7) ^ (row & 7);
      gload_lds16(Bg + (size_t)(bn0 + row) * Kd + kt + sc * 8, db + idx * 16);
    }
  };

  auto compute = [&](int buf) {
    const char* Ab = smem + buf * 32768;
    const char* Bb = Ab + 16384;
#pragma unroll
    for (int kk = 0; kk < 2; ++kk) {
      int ch = ((kk * 4 + q16) ^ sw) * 16;
      bf16x8 af[4], bfr[4];
#pragma unroll
      for (int i = 0; i < 4; ++i)
        af[i] = *(const bf16x8*)(Ab + (wr * 64 + i * 16 + r16) * 128 + ch);
#pragma unroll
      for (int j = 0; j < 4; ++j)
        bfr[j] = *(const bf16x8*)(Bb + (wc * 64 + j * 16 + r16) * 128 + ch);
#pragma unroll
      for (int i = 0; i < 4; ++i)
#pragma unroll
        for (int j = 0; j < 4; ++j)
          acc[i][j] = __builtin_amdgcn_mfma_f32_16x16x32_bf16(af[i], bfr[j], acc[i][j], 0, 0, 0);
    }
  };

  const int NT = Kd >> 6;           // Kd in {256,1024,2048} -> NT in {4,16,32}
  stage(0, 0);
  int t = 0;
  for (; t < NT - 1; ++t) {
    stage((t + 1) & 1, (t + 1) * 64);
    asm volatile("s_waitcnt vmcnt(8)" ::: "memory");
    __builtin_amdgcn_s_barrier();
    __builtin_amdgcn_sched_barrier(0);
    compute(t & 1);
    __builtin_amdgcn_sched_barrier(0);
    __builtin_amdgcn_s_barrier();
  }
  asm volatile("s_waitcnt vmcnt(0)" ::: "memory");
  __builtin_amdgcn_s_barrier();
  __builtin_amdgcn_sched_barrier(0);
  compute(t & 1);

  float scale = inv_alpha ? 1.f / alpha[0] : 1.f;
#pragma unroll
  for (int i = 0; i < 4; ++i) {
#pragma unroll
    for (int j = 0; j < 4; ++j) {
#pragma unroll
      for (int e = 0; e < 4; ++e) {
        int m = bm0 + wr * 64 + i * 16 + q16 * 4 + e;
        int n = bn0 + wc * 64 + j * 16 + r16;
        size_t o = (size_t)m * N + n;
        float v = acc[i][j][e] * scale;
        if (EPI == EPI_BF16) {
          outb[o] = (bf16)v;
        } else if (EPI == EPI_F32) {
          outf[o] = v;
        } else if (EPI == EPI_TEMPS) {
          outb[o] = (bf16)v;
          out2[o] = (bf16)((m == n ? 1.f : 0.f) - v);
        } else { // EPI_W1
          outb[o] = (bf16)(srcf[o] - v);
        }
      }
    }
  }
}

// ---------------------------------------------------------------------------
// Scan GEMM: 64x64 tile, BK=128, wave-level K-split (each wave: full 64x64
// over its private K=32 slice), LDS cross-wave reduce at the end.
// Pipeline: DEPTH=4 (plain, 128KB) / DEPTH=3 (DUAL, 144KB), counted
// vmcnt(24) + raw barriers.
// XCD-PINNED N-slices: 1-D grid 256; xcd = bid&7 owns columns
// [xcd*256, xcd*256+256) of S/W1/G, so each XCD's 1MB weight slice stays
// resident in its private L2 across all 80 scan launches.
// DUAL: also computes a1 = h@G^T sharing A-fragments; stores a1 f32.
// Epilogue: h_out = soft_l1_l1(acc + xv, w0, w1, a1).
// ---------------------------------------------------------------------------
template<bool DUAL>
__global__ __launch_bounds__(256)
void gemm_scan(const bf16* __restrict__ Ag, const bf16* __restrict__ B1g,
               const bf16* __restrict__ B2g, int N, int Kd,
               const bf16* __restrict__ xv, const float* __restrict__ a1in,
               float* __restrict__ a1out, bf16* __restrict__ outb,
               const float* __restrict__ alpha, const float* __restrict__ lam0,
               const float* __restrict__ lam1)
{
  constexpr int HALF = DUAL ? 49152 : 32768;   // per-buffer bytes
  constexpr int D = DUAL ? 3 : 4;
  constexpr int SMEM = HALF * D;               // 147456 / 131072; >= reduce 77824
  __shared__ char smem[SMEM];
  const int tid = threadIdx.x, lane = tid & 63, wid = tid >> 6;
  const int r16 = lane & 15, q16 = lane >> 4;
  // XCD-pinned decode: xcd = bid&7 -> N-slice; r enumerates (rowtile, subn)
  const int bid = blockIdx.x;
  const int xcd = bid & 7, r = bid >> 3;
  const int bn0 = xcd * 256 + (r & 3) * 64;
  const int bm0 = (r >> 2) * 64;
  const int sw = r16 & 7;
  const int chbase = ((wid * 4 + q16) ^ sw) * 16;   // wave's K-slice chunk (swizzled)

  f32x4 accW[4][4] = {};
  f32x4 accG[4][4] = {};   // DCE'd when !DUAL

  auto stage = [&](int buf, int kt) {
    char* base = smem + buf * HALF;
#pragma unroll
    for (int it = 0; it < 4; ++it) {
      int idx = it * 256 + tid;
      int row = idx >> 4, sc = (idx & 15) ^ (row & 7);
      gload_lds16(Ag + (size_t)(bm0 + row) * Kd + kt + sc * 8, base + idx * 16);
    }
#pragma unroll
    for (int it = 0; it < 4; ++it) {
      int idx = it * 256 + tid;
      int row = idx >> 4, sc = (idx & 15) ^ (row & 7);
      gload_lds16(B1g + (size_t)(bn0 + row) * Kd + kt + sc * 8, base + 16384 + idx * 16);
    }
    if constexpr (DUAL) {
#pragma unroll
      for (int it = 0; it < 4; ++it) {
        int idx = it * 256 + tid;
        int row = idx >> 4, sc = (idx & 15) ^ (row & 7);
        gload_lds16(B2g + (size_t)(bn0 + row) * Kd + kt + sc * 8, base + 32768 + idx * 16);
      }
    }
  };

  auto compute = [&](int buf) {
    const char* Ab = smem + buf * HALF;
    const char* B1b = Ab + 16384;
    bf16x8 af[4], b1[4];
#pragma unroll
    for (int i = 0; i < 4; ++i)
      af[i] = *(const bf16x8*)(Ab + (i * 16 + r16) * 256 + chbase);
#pragma unroll
    for (int j = 0; j < 4; ++j)
      b1[j] = *(const bf16x8*)(B1b + (j * 16 + r16) * 256 + chbase);
#pragma unroll
    for (int i = 0; i < 4; ++i)
#pragma unroll
      for (int j = 0; j < 4; ++j)
        accW[i][j] = __builtin_amdgcn_mfma_f32_16x16x32_bf16(af[i], b1[j], accW[i][j], 0, 0, 0);
    if constexpr (DUAL) {
      const char* B2b = Ab + 32768;
      bf16x8 b2[4];
#pragma unroll
      for (int j = 0; j < 4; ++j)
        b2[j] = *(const bf16x8*)(B2b + (j * 16 + r16) * 256 + chbase);
#pragma unroll
      for (int i = 0; i < 4; ++i)
#pragma unroll
        for (int j = 0; j < 4; ++j)
          accG[i][j] = __builtin_amdgcn_mfma_f32_16x16x32_bf16(af[i], b2[j], accG[i][j], 0, 0, 0);
    }
  };

  const int NT = Kd >> 7;   // 16
  for (int p = 0; p < D - 1; ++p) stage(p, p * 128);
  int sbuf = D - 1, cbuf = 0, t = 0;
  for (; t < NT - (D - 1); ++t) {
    stage(sbuf, (t + D - 1) * 128);
    sbuf = (sbuf + 1 == D) ? 0 : sbuf + 1;
    asm volatile("s_waitcnt vmcnt(24)" ::: "memory");
    __builtin_amdgcn_s_barrier();
    __builtin_amdgcn_sched_barrier(0);
    compute(cbuf);
    __builtin_amdgcn_sched_barrier(0);
    __builtin_amdgcn_s_barrier();
    cbuf = (cbuf + 1 == D) ? 0 : cbuf + 1;
  }
  asm volatile("s_waitcnt vmcnt(0)" ::: "memory");
  __builtin_amdgcn_s_barrier();
  __builtin_amdgcn_sched_barrier(0);
  for (; t < NT; ++t) {
    compute(cbuf);
    cbuf = (cbuf + 1 == D) ? 0 : cbuf + 1;
  }
  __syncthreads();

  // cross-wave K-reduce via LDS (aliases staging; all loads drained above)
  float* red = (float*)smem;
  const int myrow = (wid * 64 + lane) * 76;
  const int lrow = lane * 76;
  f32x4 sg[4];
  if constexpr (DUAL) {
#pragma unroll
    for (int i = 0; i < 4; ++i)
#pragma unroll
      for (int j = 0; j < 4; ++j)
        *(f32x4*)&red[myrow + (i * 4 + j) * 4] = accG[i][j];
    __syncthreads();
#pragma unroll
    for (int j = 0; j < 4; ++j) {
      sg[j] = *(const f32x4*)&red[lrow + wid * 16 + j * 4];
#pragma unroll
      for (int w = 1; w < 4; ++w)
        sg[j] += *(const f32x4*)&red[w * 4864 + lrow + wid * 16 + j * 4];
    }
    __syncthreads();
  }
#pragma unroll
  for (int i = 0; i < 4; ++i)
#pragma unroll
    for (int j = 0; j < 4; ++j)
      *(f32x4*)&red[myrow + (i * 4 + j) * 4] = accW[i][j];
  __syncthreads();
  f32x4 sz[4];
#pragma unroll
  for (int j = 0; j < 4; ++j) {
    sz[j] = *(const f32x4*)&red[lrow + wid * 16 + j * 4];
#pragma unroll
    for (int w = 1; w < 4; ++w)
      sz[j] += *(const f32x4*)&red[w * 4864 + lrow + wid * 16 + j * 4];
  }

  float al = alpha[0];
  float w0 = lam0[0] / al, w1 = lam1[0] / al;
#pragma unroll
  for (int j = 0; j < 4; ++j) {
#pragma unroll
    for (int e = 0; e < 4; ++e) {
      int m = bm0 + wid * 16 + q16 * 4 + e;   // wave wid reduced frag-row i == wid
      int n = bn0 + j * 16 + r16;
      size_t o = (size_t)m * N + n;
      float a1v;
      if constexpr (DUAL) { a1v = sg[j][e]; a1out[o] = a1v; }
      else                { a1v = a1in[o]; }
      float z = sz[j][e] + (float)xv[o];
      outb[o] = (bf16)soft_l1_l1(z, w0, w1, a1v);
    }
  }
}

__global__ void cast_f32_bf16(const float* __restrict__ in, bf16* __restrict__ out, int n) {
  int i = (blockIdx.x * blockDim.x + threadIdx.x) * 4;
  if (i + 4 <= n) {
    float4 v = *(const float4*)&in[i];
    bf16x4 p;
    p[0] = (bf16)v.x; p[1] = (bf16)v.y; p[2] = (bf16)v.z; p[3] = (bf16)v.w;
    *(bf16x4*)&out[i] = p;
  } else {
    for (; i < n; ++i) out[i] = (bf16)in[i];
  }
}

// out[c,r] = (bf16) in[r,c];  in: [R,C] f32 row-major -> out: [C,R] bf16 row-major
__global__ void transpose_cast(const float* __restrict__ in, bf16* __restrict__ out, int R, int C) {
  __shared__ float tile[32][33];
  int bx = blockIdx.x * 32, by = blockIdx.y * 32;
  int tx = threadIdx.x, ty = threadIdx.y;
  for (int i = ty; i < 32; i += 8) {
    int r = by + i, c = bx + tx;
    if (r < R && c < C) tile[i][tx] = in[(size_t)r * C + c];
  }
  __syncthreads();
  for (int i = ty; i < 32; i += 8) {
    int r = bx + i, c = by + tx;
    if (r < C && c < R) out[(size_t)r * R + c] = (bf16)tile[tx][i];
  }
}

extern "C" void kernel_launch(void* const* d_in, const int* in_sizes, int n_in,
                              void* d_out, int out_size, void* d_ws, size_t ws_size,
                              hipStream_t stream) {
  // inputs: 0 pre_input (unused), 1 raw, 2 A, 3 D, 4 G, 5 h_0,
  //         6 alpha, 7 lambda0, 8 lambda1, 9 K (fixed = 5)
  const float* rawf = (const float*)d_in[1];
  const float* Af   = (const float*)d_in[2];
  const float* Df   = (const float*)d_in[3];
  const float* Gf   = (const float*)d_in[4];
  const float* h0f  = (const float*)d_in[5];
  const float* alp  = (const float*)d_in[6];
  const float* l0   = (const float*)d_in[7];
  const float* l1   = (const float*)d_in[8];
  float* outp = (float*)d_out;

  char* w = (char*)d_ws;
  auto allocb = [&](size_t bytes) { char* p = w; w += (bytes + 255) & ~(size_t)255; return p; };
  bf16* Abf  = (bf16*)allocb((size_t)NI * NF * 2);
  bf16* At   = (bf16*)allocb((size_t)NF * NI * 2);
  bf16* Dbf  = (bf16*)allocb((size_t)NF * NH * 2);
  bf16* Dt   = (bf16*)allocb((size_t)NH * NF * 2);
  bf16* Gt   = (bf16*)allocb((size_t)NH * NH * 2);
  bf16* rawb = (bf16*)allocb((size_t)T_STEPS * BB * NF * 2);
  bf16* AtA  = (bf16*)allocb((size_t)NF * NF * 2);
  bf16* Vm   = (bf16*)allocb((size_t)NH * NI * 2);
  bf16* M3t  = (bf16*)allocb((size_t)NH * NF * 2);
  bf16* tmpb = (bf16*)allocb((size_t)NH * NH * 2);
  bf16* Sm   = (bf16*)allocb((size_t)NH * NH * 2);
  bf16* W1m  = (bf16*)allocb((size_t)NH * NH * 2);
  bf16* X    = (bf16*)allocb((size_t)T_STEPS * BB * NI * 2);
  float* A1f = (float*)allocb((size_t)BB * NH * 4);
  bf16* H0   = (bf16*)allocb((size_t)BB * NH * 2);
  bf16* Hb0  = (bf16*)allocb((size_t)BB * NH * 2);
  bf16* Hb1  = (bf16*)allocb((size_t)BB * NH * 2);
  bf16* HS   = (bf16*)allocb((size_t)T_STEPS * BB * NH * 2);
  // XV (T*B x NH bf16 = 32 MB) lives in d_out: fully written before use, dead
  // before the final projection overwrites d_out.
  bf16* XV   = (bf16*)d_out;

  auto cgrid = [](int n) { return dim3((unsigned)((n / 4 + 255) / 256)); };
  cast_f32_bf16<<<cgrid(NI * NF), 256, 0, stream>>>(Af, Abf, NI * NF);
  cast_f32_bf16<<<cgrid(NF * NH), 256, 0, stream>>>(Df, Dbf, NF * NH);
  cast_f32_bf16<<<cgrid(T_STEPS * BB * NF), 256, 0, stream>>>(rawf, rawb, T_STEPS * BB * NF);
  cast_f32_bf16<<<cgrid(BB * NH), 256, 0, stream>>>(h0f, H0, BB * NH);
  transpose_cast<<<dim3(NF / 32, NI / 32), dim3(32, 8), 0, stream>>>(Af, At, NI, NF);
  transpose_cast<<<dim3(NH / 32, NF / 32), dim3(32, 8), 0, stream>>>(Df, Dt, NF, NH);
  transpose_cast<<<dim3(NH / 32, NH / 32), dim3(32, 8), 0, stream>>>(Gf, Gt, NH, NH);

  auto launch_bt2 = [&](auto epi_tag, int Mrows, int Ncols, int Kd,
                        const bf16* Ap, const bf16* Bp,
                        bf16* ob, float* of, bf16* o2, const float* sf, int inva) {
    constexpr int EPIv = decltype(epi_tag)::value;
    int nbx = Mrows / 128, nby = Ncols / 128, total = nbx * nby;
    gemm_bt2<EPIv><<<dim3(total), 256, 0, stream>>>(
        Ap, Bp, Ncols, Kd, nbx, total, ob, of, o2, sf, alp, inva);
  };

  // AtA[f1,f2] = sum_i A[i,f1]A[i,f2]
  launch_bt2(std::integral_constant<int, EPI_BF16>{}, NF, NF, NI, At, At,
             AtA, nullptr, nullptr, nullptr, 0);
  // V[h,i] = (1/al) sum_f D[f,h]A[i,f]
  launch_bt2(std::integral_constant<int, EPI_BF16>{}, NH, NI, NF, Dt, Abf,
             Vm, nullptr, nullptr, nullptr, 1);
  // M3t[h,f] = sum_f2 Dt[h,f2]AtA[f,f2] = (AtA@D)[f,h]  (AtA symmetric)
  launch_bt2(std::integral_constant<int, EPI_BF16>{}, NH, NF, NF, Dt, AtA,
             M3t, nullptr, nullptr, nullptr, 0);
  // temp = (1/al) D^T (AtA D); S = I - temp (dual store)
  launch_bt2(std::integral_constant<int, EPI_TEMPS>{}, NH, NH, NF, Dt, M3t,
             tmpb, nullptr, Sm, nullptr, 1);
  // W1 = G - temp@G
  launch_bt2(std::integral_constant<int, EPI_W1>{}, NH, NH, NH, tmpb, Gt,
             W1m, nullptr, nullptr, Gf, 0);
  // X = raw @ A^T
  launch_bt2(std::integral_constant<int, EPI_BF16>{}, T_STEPS * BB, NI, NF, rawb, Abf,
             X, nullptr, nullptr, nullptr, 0);
  // XV = X @ V^T
  launch_bt2(std::integral_constant<int, EPI_BF16>{}, T_STEPS * BB, NH, NI, X, Vm,
             XV, nullptr, nullptr, nullptr, 0);

  const size_t HBsz = (size_t)BB * NH;
  const bf16* hp = H0;
  for (int t = 0; t < T_STEPS; ++t) {
    const bf16* xvt = XV + (size_t)t * HBsz;
    bf16* dsts[KSTEPS];
    for (int k = 0; k < KSTEPS; ++k) dsts[k] = (k & 1) ? Hb1 : Hb0;
    dsts[KSTEPS - 1] = HS + (size_t)t * HBsz;
    // k=0: h = shrink(h@W1^T + xv, a1 = h@G) — a1 fused (dual-B), stored f32
    gemm_scan<true><<<dim3(256), 256, 0, stream>>>(
        hp, W1m, Gt, NH, NH, xvt, nullptr, A1f, dsts[0], alp, l0, l1);
    const bf16* cur = dsts[0];
    for (int k = 1; k < KSTEPS; ++k) {
      // h = shrink(xv + h@S^T)
      gemm_scan<false><<<dim3(256), 256, 0, stream>>>(
          cur, Sm, nullptr, NH, NH, xvt, A1f, nullptr, dsts[k], alp, l0, l1);
      cur = dsts[k];
    }
    hp = HS + (size_t)t * HBsz;
  }
  // z_hat = HS @ D^T (fp32 direct to d_out)
  launch_bt2(std::integral_constant<int, EPI_F32>{}, T_STEPS * BB, NF, NH, HS, Dbf,
             nullptr, outp, nullptr, nullptr, 0);
}